// Round 9
// baseline (259.184 us; speedup 1.0000x reference)
//
#include <hip/hip_runtime.h>
#include <math.h>

#define BB 128
#define SS 200
#define MM 50
#define DKK 64
#define DVV 128
#define FF 64
#define NROW (BB*SS)   // 25600

// w padded layout: direct m index, 64 floats/row, m in [0,50) valid, rest zero
#define WROW 64
#define NCH 16         // scan chunks (= waves per block)
#define NFCB (NROW/64) // 400 k_fc blocks
#define WLDS 136       // k_ea LDS bf16 row stride (128 + 8 pad -> 2-way bank alias, free)

// workspace layout (floats)
#define W_OFF   0L
#define EA_OFF  (W_OFF + (long)NROW*WROW)        // interleaved (e,a) float2
#define R_OFF   (EA_OFF + (long)NROW*DVV*2)
#define ACC_OFF (R_OFF + (long)NROW*DVV)         // NFCB float2 partials

typedef __attribute__((ext_vector_type(8))) short bf16x8;   // 8 bf16 (4 VGPRs)
typedef __attribute__((ext_vector_type(4))) float f32x4;

__device__ __forceinline__ float rlane(float v, int l) {
    return __builtin_bit_cast(float, __builtin_amdgcn_readlane(__builtin_bit_cast(unsigned, v), l));
}
__device__ __forceinline__ short f2bf(float f) {   // RNE fp32->bf16
    unsigned u = __builtin_bit_cast(unsigned, f);
    u += 0x7fff + ((u >> 16) & 1);
    return (short)(u >> 16);
}

// ---------------- Kernel 1: w = softmax(q_e @ mem_key^T) ----------------
__global__ __launch_bounds__(128) void k_scores(const int* __restrict__ q_data,
                                                const float* __restrict__ q_embed_w,
                                                const float* __restrict__ mem_key,
                                                float* __restrict__ w_out) {
    __shared__ float4 mk[MM * 16];   // 12.8 KB
    int tid = threadIdx.x;
    const float4* mkg = (const float4*)mem_key;
    for (int i = tid; i < MM * 16; i += 128) mk[i] = mkg[i];
    __syncthreads();

    int item = blockIdx.x * 128 + tid;
    int qidx = q_data[item];
    const float4* qg = (const float4*)(q_embed_w + (long)qidx * DKK);
    float4 q[16];
#pragma unroll
    for (int i = 0; i < 16; i++) q[i] = qg[i];

    float s[MM];
    float mx = -1e30f;
#pragma unroll 2
    for (int m = 0; m < MM; m++) {
        float a = 0.f;
#pragma unroll
        for (int k4 = 0; k4 < 16; k4++) {
            float4 mkv = mk[m * 16 + k4];
            float4 qv = q[k4];
            a = fmaf(qv.x, mkv.x, a);
            a = fmaf(qv.y, mkv.y, a);
            a = fmaf(qv.z, mkv.z, a);
            a = fmaf(qv.w, mkv.w, a);
        }
        s[m] = a;
        mx = fmaxf(mx, a);
    }
    float sum = 0.f;
#pragma unroll
    for (int m = 0; m < MM; m++) { s[m] = expf(s[m] - mx); sum += s[m]; }
    float inv = 1.f / sum;

    float* wo = w_out + (long)item * WROW;
#pragma unroll
    for (int m = 0; m < MM; m++) wo[m] = s[m] * inv;
#pragma unroll
    for (int m = MM; m < WROW; m++) wo[m] = 0.f;
}

// ---------------- Kernel 2: e/a GEMM via bf16 MFMA ----------------
// Block = 64 rows x 128 v, 4 waves (wave w: rows r0+16w..+15).
// W (both mats) staged once in LDS as bf16, stride 136; qa A-frags gathered
// global->reg with RNE convert. Per wave: 8 vtiles x (8 ds_read_b128 + 8 MFMA).
// D layout: col(v)=lane&15, row=quad*4+reg -> e,a for same (row,v) in same lane.
__global__ __launch_bounds__(256) void k_ea(const int* __restrict__ qa_data,
                                            const float* __restrict__ qa_embed_w,
                                            const float* __restrict__ erase_w,
                                            const float* __restrict__ erase_b,
                                            const float* __restrict__ add_w,
                                            const float* __restrict__ add_b,
                                            float* __restrict__ EA) {
    __shared__ short Wl[2 * 128 * WLDS];   // 69.6 KB
    int tid = threadIdx.x;
    int r0 = blockIdx.x * 64;
    int lane = tid & 63;
    int wv = tid >> 6;          // wave 0..3
    int n = lane & 15;
    int quad = lane >> 4;       // 0..3

    // stage both weight matrices as bf16 (32 float4 per thread)
    for (int i = tid; i < 8192; i += 256) {
        int mat = i >> 12;
        int r = (i >> 5) & 127;
        int p = i & 31;
        float4 src = *(const float4*)((mat ? add_w : erase_w) + r * 128 + p * 4);
        short4 d;
        d.x = f2bf(src.x); d.y = f2bf(src.y); d.z = f2bf(src.z); d.w = f2bf(src.w);
        *(short4*)(Wl + (mat * 128 + r) * WLDS + p * 4) = d;
    }

    // A-frags: lane holds qa row (r0 + wv*16 + n), k = kb*32 + quad*8 + j
    int arow = r0 + wv * 16 + n;
    int qidx = qa_data[arow];
    const float* qp = qa_embed_w + (long)qidx * DVV + quad * 8;
    bf16x8 afrag[4];
#pragma unroll
    for (int kb = 0; kb < 4; kb++) {
        float4 lo = *(const float4*)(qp + kb * 32);
        float4 hi = *(const float4*)(qp + kb * 32 + 4);
        bf16x8 f;
        f[0] = f2bf(lo.x); f[1] = f2bf(lo.y); f[2] = f2bf(lo.z); f[3] = f2bf(lo.w);
        f[4] = f2bf(hi.x); f[5] = f2bf(hi.y); f[6] = f2bf(hi.z); f[7] = f2bf(hi.w);
        afrag[kb] = f;
    }

    float eb_[8], ab_[8];
#pragma unroll
    for (int vt = 0; vt < 8; vt++) {
        eb_[vt] = erase_b[vt * 16 + n];
        ab_[vt] = add_b[vt * 16 + n];
    }
    __syncthreads();

    int rowbase = r0 + wv * 16 + quad * 4;
#pragma unroll 2
    for (int vt = 0; vt < 8; vt++) {
        int vrow = vt * 16 + n;     // B-frag: lane's column = W row (B^T pattern)
        f32x4 ae = {0.f, 0.f, 0.f, 0.f};
        f32x4 aa = {0.f, 0.f, 0.f, 0.f};
#pragma unroll
        for (int kb = 0; kb < 4; kb++) {
            bf16x8 be = *(const bf16x8*)(Wl + vrow * WLDS + kb * 32 + quad * 8);
            bf16x8 ba = *(const bf16x8*)(Wl + (128 + vrow) * WLDS + kb * 32 + quad * 8);
            ae = __builtin_amdgcn_mfma_f32_16x16x32_bf16(afrag[kb], be, ae, 0, 0, 0);
            aa = __builtin_amdgcn_mfma_f32_16x16x32_bf16(afrag[kb], ba, aa, 0, 0, 0);
        }
        int v = vt * 16 + n;
        float eb = eb_[vt], ab = ab_[vt];
#pragma unroll
        for (int r = 0; r < 4; r++) {
            float ev = 1.f / (1.f + __expf(-(ae[r] + eb)));
            float av = 2.f / (1.f + __expf(-2.f * (aa[r] + ab))) - 1.f;
            float2 o; o.x = ev; o.y = av;
            *(float2*)(EA + (((long)(rowbase + r)) * DVV + v) * 2) = o;
        }
    }
}

// ---------------- Kernel 3: chunked affine scan — 16 chunks, 1024 threads ----------------
// Mv_t = alpha_t*Mv_{t-1} + beta_t; chunks of 13/12 steps; 16 waves = 4/SIMD.
__global__ __launch_bounds__(1024, 1) void k_scan(const float* __restrict__ w_pad,
                                                  const float* __restrict__ EA,
                                                  const float* __restrict__ init_mv,
                                                  float* __restrict__ R) {
    __shared__ float Sb[MM * 64];      // 12.8 KB boundary state
    int b   = blockIdx.x >> 1;
    int vh  = blockIdx.x & 1;
    int tid = threadIdx.x;
    int lane  = tid & 63;
    int chunk = tid >> 6;              // wave id = chunk (0..15)
    int v  = vh * 64 + lane;
    int cl = (chunk < 8) ? 13 : 12;
    int t0 = (chunk < 8) ? chunk * 13 : 104 + (chunk - 8) * 12;

    const float* wbase = w_pad + ((long)b * SS + t0) * WROW;
    const float* eab   = EA + (((long)b * SS + t0) * DVV + v) * 2;
    float*       Rb    = R + ((long)b * SS + t0) * DVV + v;

    // ---- pass 1: compose the chunk's affine map per m ----
    float A[MM], Bc[MM];
#pragma unroll
    for (int m = 0; m < MM; m++) { A[m] = 1.f; Bc[m] = 0.f; }

    float  w_cur  = wbase[lane];
    float2 ea_cur = *(const float2*)eab;
#pragma unroll 1
    for (int t = 0; t < cl; t++) {
        int tp = (t + 1 < cl) ? t + 1 : t;
        float  w_nxt  = wbase[tp * WROW + lane];
        float2 ea_nxt = *(const float2*)(eab + (long)tp * DVV * 2);
        float e = ea_cur.x, a = ea_cur.y;
#pragma unroll
        for (int m = 0; m < MM; m++) {
            float wm = rlane(w_cur, m);
            float alpha = fmaf(-wm, e, 1.f);
            A[m] *= alpha;
            Bc[m] = fmaf(alpha, Bc[m], wm * a);
        }
        w_cur = w_nxt; ea_cur = ea_nxt;
    }

    // ---- combine: sequential over waves through LDS ----
    float Mv[MM];
    if (chunk == 0) {
#pragma unroll
        for (int m = 0; m < MM; m++) Mv[m] = init_mv[m * DVV + v];
#pragma unroll
        for (int m = 0; m < MM; m++) Sb[m * 64 + lane] = fmaf(A[m], Mv[m], Bc[m]);
    }
    __syncthreads();
    for (int c = 1; c < NCH; c++) {
        if (chunk == c) {
#pragma unroll
            for (int m = 0; m < MM; m++) Mv[m] = Sb[m * 64 + lane];
            if (c + 1 < NCH) {
#pragma unroll
                for (int m = 0; m < MM; m++) Sb[m * 64 + lane] = fmaf(A[m], Mv[m], Bc[m]);
            }
        }
        __syncthreads();
    }

    // ---- pass 2: replay chunk, emitting reads (pre-update Mv) ----
    w_cur  = wbase[lane];
    ea_cur = *(const float2*)eab;
#pragma unroll 1
    for (int t = 0; t < cl; t++) {
        int tp = (t + 1 < cl) ? t + 1 : t;
        float  w_nxt  = wbase[tp * WROW + lane];
        float2 ea_nxt = *(const float2*)(eab + (long)tp * DVV * 2);
        float e = ea_cur.x, a = ea_cur.y;
        float rd0 = 0.f, rd1 = 0.f;
#pragma unroll
        for (int m = 0; m < MM; m += 2) {
            float wm0 = rlane(w_cur, m);
            rd0 = fmaf(wm0, Mv[m], rd0);
            float al0 = fmaf(-wm0, e, 1.f);
            Mv[m] = fmaf(al0, Mv[m], wm0 * a);
            float wm1 = rlane(w_cur, m + 1);
            rd1 = fmaf(wm1, Mv[m + 1], rd1);
            float al1 = fmaf(-wm1, e, 1.f);
            Mv[m + 1] = fmaf(al1, Mv[m + 1], wm1 * a);
        }
        Rb[t * DVV] = rd0 + rd1;
        w_cur = w_nxt; ea_cur = ea_nxt;
    }
}

// ---------------- Kernel 4: FC head + BCE — NO global atomics ----------------
__global__ __launch_bounds__(256) void k_fc(const float* __restrict__ Rr,
                                            const int* __restrict__ q_data,
                                            const float* __restrict__ q_embed_w,
                                            const float* __restrict__ read_w,
                                            const float* __restrict__ read_b,
                                            const float* __restrict__ pred_w,
                                            const float* __restrict__ pred_b,
                                            const float* __restrict__ target,
                                            float* __restrict__ out,
                                            float2* __restrict__ part) {
    __shared__ float Wl[64 * 196];   // 50.2 KB
    __shared__ float xl[64 * 100];   // 25.6 KB
    __shared__ float2 red[4];
    int tid = threadIdx.x;
    int r0 = blockIdx.x * 64;
    int fq = tid & 15;
    int rh = tid >> 4;   // 0..15

    for (int i = tid; i < 3072; i += 256) {
        int f = i / 48, p = i - f * 48;
        *(float4*)(Wl + f * 196 + p * 4) = *(const float4*)(read_w + f * 192 + p * 4);
    }

    float accv[4][4];
#pragma unroll
    for (int i = 0; i < 4; i++)
#pragma unroll
        for (int j = 0; j < 4; j++) accv[i][j] = 0.f;

    for (int kc = 0; kc < 2; kc++) {
        __syncthreads();
        for (int i = tid; i < 1536; i += 256) {
            int r = i / 24, p = i - r * 24;
            float4 val;
            if (kc == 0) {
                val = *(const float4*)(Rr + (long)(r0 + r) * DVV + p * 4);
            } else if (p < 8) {
                val = *(const float4*)(Rr + (long)(r0 + r) * DVV + 96 + p * 4);
            } else {
                int qi = q_data[r0 + r];
                val = *(const float4*)(q_embed_w + (long)qi * DKK + (p - 8) * 4);
            }
            *(float4*)(xl + r * 100 + p * 4) = val;
        }
        __syncthreads();
#pragma unroll 4
        for (int kk = 0; kk < 96; kk += 4) {
            float4 wv[4], x4[4];
#pragma unroll
            for (int i = 0; i < 4; i++)
                wv[i] = *(const float4*)(Wl + (fq + 16 * i) * 196 + kc * 96 + kk);
#pragma unroll
            for (int j = 0; j < 4; j++)
                x4[j] = *(const float4*)(xl + (rh * 4 + j) * 100 + kk);
#pragma unroll
            for (int i = 0; i < 4; i++)
#pragma unroll
                for (int j = 0; j < 4; j++) {
                    accv[i][j] = fmaf(x4[j].x, wv[i].x, accv[i][j]);
                    accv[i][j] = fmaf(x4[j].y, wv[i].y, accv[i][j]);
                    accv[i][j] = fmaf(x4[j].z, wv[i].z, accv[i][j]);
                    accv[i][j] = fmaf(x4[j].w, wv[i].w, accv[i][j]);
                }
        }
    }

    float pb = pred_b[0];
    float rb_[4], pw_[4];
#pragma unroll
    for (int i = 0; i < 4; i++) { rb_[i] = read_b[fq + 16 * i]; pw_[i] = pred_w[fq + 16 * i]; }

    float bce_sum = 0.f, cnt = 0.f;
#pragma unroll
    for (int j = 0; j < 4; j++) {
        float pv = 0.f;
#pragma unroll
        for (int i = 0; i < 4; i++)
            pv = fmaf(pw_[i], tanhf(accv[i][j] + rb_[i]), pv);
        pv += __shfl_xor(pv, 1, 64);
        pv += __shfl_xor(pv, 2, 64);
        pv += __shfl_xor(pv, 4, 64);
        pv += __shfl_xor(pv, 8, 64);
        if (fq == 0) {
            int row = r0 + rh * 4 + j;
            float tgt = target[row];
            float logit = pv + pb;
            float prob = 0.f;
            if (tgt >= 0.f) {
                prob = 1.f / (1.f + expf(-logit));
                float bce = fmaxf(logit, 0.f) - logit * tgt + log1pf(expf(-fabsf(logit)));
                bce_sum += bce;
                cnt += 1.f;
            }
            out[1 + row] = prob;
        }
    }
    bce_sum += __shfl_xor(bce_sum, 16, 64);
    bce_sum += __shfl_xor(bce_sum, 32, 64);
    cnt     += __shfl_xor(cnt, 16, 64);
    cnt     += __shfl_xor(cnt, 32, 64);
    int lane = tid & 63, wid = tid >> 6;
    if (lane == 0) { red[wid].x = bce_sum; red[wid].y = cnt; }
    __syncthreads();
    if (tid == 0) {
        float2 p;
        p.x = red[0].x + red[1].x + red[2].x + red[3].x;
        p.y = red[0].y + red[1].y + red[2].y + red[3].y;
        part[blockIdx.x] = p;
    }
}

// ---------------- Kernel 5: reduce partials -> loss ----------------
__global__ __launch_bounds__(256) void k_loss(const float2* __restrict__ part,
                                              float* __restrict__ out) {
    __shared__ float2 red[4];
    int tid = threadIdx.x;
    float b = 0.f, c = 0.f;
    for (int i = tid; i < NFCB; i += 256) {
        float2 p = part[i];
        b += p.x; c += p.y;
    }
#pragma unroll
    for (int off = 32; off; off >>= 1) {
        b += __shfl_xor(b, off, 64);
        c += __shfl_xor(c, off, 64);
    }
    int lane = tid & 63, wid = tid >> 6;
    if (lane == 0) { red[wid].x = b; red[wid].y = c; }
    __syncthreads();
    if (tid == 0) {
        float B = red[0].x + red[1].x + red[2].x + red[3].x;
        float C = red[0].y + red[1].y + red[2].y + red[3].y;
        out[0] = B / fmaxf(C, 1.f);
    }
}

extern "C" void kernel_launch(void* const* d_in, const int* in_sizes, int n_in,
                              void* d_out, int out_size, void* d_ws, size_t ws_size,
                              hipStream_t stream) {
    const int*   q_data     = (const int*)d_in[0];
    const int*   qa_data    = (const int*)d_in[1];
    const float* target     = (const float*)d_in[2];
    const float* q_embed_w  = (const float*)d_in[3];
    const float* qa_embed_w = (const float*)d_in[4];
    const float* mem_key    = (const float*)d_in[5];
    const float* init_mv    = (const float*)d_in[6];
    const float* erase_w    = (const float*)d_in[7];
    const float* erase_b    = (const float*)d_in[8];
    const float* add_w      = (const float*)d_in[9];
    const float* add_b      = (const float*)d_in[10];
    const float* read_w     = (const float*)d_in[11];
    const float* read_b     = (const float*)d_in[12];
    const float* pred_w     = (const float*)d_in[13];
    const float* pred_b     = (const float*)d_in[14];
    float* out = (float*)d_out;
    float* ws  = (float*)d_ws;

    float*  w_all = ws + W_OFF;
    float*  EA    = ws + EA_OFF;
    float*  R     = ws + R_OFF;
    float2* part  = (float2*)(ws + ACC_OFF);

    k_scores<<<NROW / 128, 128, 0, stream>>>(q_data, q_embed_w, mem_key, w_all);
    k_ea<<<NROW / 64, 256, 0, stream>>>(qa_data, qa_embed_w, erase_w, erase_b,
                                        add_w, add_b, EA);
    k_scan<<<BB * 2, 1024, 0, stream>>>(w_all, EA, init_mv, R);
    k_fc<<<NFCB, 256, 0, stream>>>(R, q_data, q_embed_w, read_w, read_b,
                                   pred_w, pred_b, target, out, part);
    k_loss<<<1, 256, 0, stream>>>(part, out);
}

// Round 10
// 246.776 us; speedup vs baseline: 1.0503x; 1.0503x over previous
//
#include <hip/hip_runtime.h>
#include <math.h>

#define BB 128
#define SS 200
#define MM 50
#define DKK 64
#define DVV 128
#define FF 64
#define NROW (BB*SS)   // 25600

// w padded layout: direct m index, 64 floats/row, m in [0,50) valid, rest zero
#define WROW 64
#define NFCB (NROW/64) // 400 k_fc blocks
#define WLDS 136       // k_ea LDS bf16 row stride (128 + 8 pad -> 2-way bank alias, free)
#define CLEN 25        // scan: steps per t-chunk
#define MH 25          // scan: m-slots per thread (half of 50)

// workspace layout (floats)
#define W_OFF   0L
#define EA_OFF  (W_OFF + (long)NROW*WROW)        // interleaved (e,a) float2
#define R_OFF   (EA_OFF + (long)NROW*DVV*2)
#define ACC_OFF (R_OFF + (long)NROW*DVV)         // NFCB float2 partials

typedef __attribute__((ext_vector_type(8))) short bf16x8;   // 8 bf16 (4 VGPRs)
typedef __attribute__((ext_vector_type(4))) float f32x4;

__device__ __forceinline__ float rlane(float v, int l) {
    return __builtin_bit_cast(float, __builtin_amdgcn_readlane(__builtin_bit_cast(unsigned, v), l));
}
__device__ __forceinline__ short f2bf(float f) {   // RNE fp32->bf16
    unsigned u = __builtin_bit_cast(unsigned, f);
    u += 0x7fff + ((u >> 16) & 1);
    return (short)(u >> 16);
}

// ---------------- Kernel 1: w = softmax(q_e @ mem_key^T) ----------------
__global__ __launch_bounds__(128) void k_scores(const int* __restrict__ q_data,
                                                const float* __restrict__ q_embed_w,
                                                const float* __restrict__ mem_key,
                                                float* __restrict__ w_out) {
    __shared__ float4 mk[MM * 16];   // 12.8 KB
    int tid = threadIdx.x;
    const float4* mkg = (const float4*)mem_key;
    for (int i = tid; i < MM * 16; i += 128) mk[i] = mkg[i];
    __syncthreads();

    int item = blockIdx.x * 128 + tid;
    int qidx = q_data[item];
    const float4* qg = (const float4*)(q_embed_w + (long)qidx * DKK);
    float4 q[16];
#pragma unroll
    for (int i = 0; i < 16; i++) q[i] = qg[i];

    float s[MM];
    float mx = -1e30f;
#pragma unroll 2
    for (int m = 0; m < MM; m++) {
        float a = 0.f;
#pragma unroll
        for (int k4 = 0; k4 < 16; k4++) {
            float4 mkv = mk[m * 16 + k4];
            float4 qv = q[k4];
            a = fmaf(qv.x, mkv.x, a);
            a = fmaf(qv.y, mkv.y, a);
            a = fmaf(qv.z, mkv.z, a);
            a = fmaf(qv.w, mkv.w, a);
        }
        s[m] = a;
        mx = fmaxf(mx, a);
    }
    float sum = 0.f;
#pragma unroll
    for (int m = 0; m < MM; m++) { s[m] = expf(s[m] - mx); sum += s[m]; }
    float inv = 1.f / sum;

    float* wo = w_out + (long)item * WROW;
#pragma unroll
    for (int m = 0; m < MM; m++) wo[m] = s[m] * inv;
#pragma unroll
    for (int m = MM; m < WROW; m++) wo[m] = 0.f;
}

// ---------------- Kernel 2: e/a GEMM via bf16 MFMA ----------------
__global__ __launch_bounds__(256) void k_ea(const int* __restrict__ qa_data,
                                            const float* __restrict__ qa_embed_w,
                                            const float* __restrict__ erase_w,
                                            const float* __restrict__ erase_b,
                                            const float* __restrict__ add_w,
                                            const float* __restrict__ add_b,
                                            float* __restrict__ EA) {
    __shared__ short Wl[2 * 128 * WLDS];   // 69.6 KB
    int tid = threadIdx.x;
    int r0 = blockIdx.x * 64;
    int lane = tid & 63;
    int wv = tid >> 6;          // wave 0..3
    int n = lane & 15;
    int quad = lane >> 4;       // 0..3

    for (int i = tid; i < 8192; i += 256) {
        int mat = i >> 12;
        int r = (i >> 5) & 127;
        int p = i & 31;
        float4 src = *(const float4*)((mat ? add_w : erase_w) + r * 128 + p * 4);
        short4 d;
        d.x = f2bf(src.x); d.y = f2bf(src.y); d.z = f2bf(src.z); d.w = f2bf(src.w);
        *(short4*)(Wl + (mat * 128 + r) * WLDS + p * 4) = d;
    }

    int arow = r0 + wv * 16 + n;
    int qidx = qa_data[arow];
    const float* qp = qa_embed_w + (long)qidx * DVV + quad * 8;
    bf16x8 afrag[4];
#pragma unroll
    for (int kb = 0; kb < 4; kb++) {
        float4 lo = *(const float4*)(qp + kb * 32);
        float4 hi = *(const float4*)(qp + kb * 32 + 4);
        bf16x8 f;
        f[0] = f2bf(lo.x); f[1] = f2bf(lo.y); f[2] = f2bf(lo.z); f[3] = f2bf(lo.w);
        f[4] = f2bf(hi.x); f[5] = f2bf(hi.y); f[6] = f2bf(hi.z); f[7] = f2bf(hi.w);
        afrag[kb] = f;
    }

    float eb_[8], ab_[8];
#pragma unroll
    for (int vt = 0; vt < 8; vt++) {
        eb_[vt] = erase_b[vt * 16 + n];
        ab_[vt] = add_b[vt * 16 + n];
    }
    __syncthreads();

    int rowbase = r0 + wv * 16 + quad * 4;
#pragma unroll 2
    for (int vt = 0; vt < 8; vt++) {
        int vrow = vt * 16 + n;
        f32x4 ae = {0.f, 0.f, 0.f, 0.f};
        f32x4 aa = {0.f, 0.f, 0.f, 0.f};
#pragma unroll
        for (int kb = 0; kb < 4; kb++) {
            bf16x8 be = *(const bf16x8*)(Wl + vrow * WLDS + kb * 32 + quad * 8);
            bf16x8 ba = *(const bf16x8*)(Wl + (128 + vrow) * WLDS + kb * 32 + quad * 8);
            ae = __builtin_amdgcn_mfma_f32_16x16x32_bf16(afrag[kb], be, ae, 0, 0, 0);
            aa = __builtin_amdgcn_mfma_f32_16x16x32_bf16(afrag[kb], ba, aa, 0, 0, 0);
        }
        int v = vt * 16 + n;
        float eb = eb_[vt], ab = ab_[vt];
#pragma unroll
        for (int r = 0; r < 4; r++) {
            float ev = 1.f / (1.f + __expf(-(ae[r] + eb)));
            float av = 2.f / (1.f + __expf(-2.f * (aa[r] + ab))) - 1.f;
            float2 o; o.x = ev; o.y = av;
            *(float2*)(EA + (((long)(rowbase + r)) * DVV + v) * 2) = o;
        }
    }
}

// ---------------- Kernel 3: chunked affine scan — 8 t-chunks x 2 m-halves ----------------
// 16 waves: tc = wave>>1 (t-chunk of 25), mh = wave&1 (m-half of 25). Per-thread
// state halved -> no spills at 4 waves/SIMD. mh wave-uniform -> readlane legal.
// rd halves combined through LDS (one barrier).
__global__ __launch_bounds__(1024, 4) void k_scan(const float* __restrict__ w_pad,
                                                  const float* __restrict__ EA,
                                                  const float* __restrict__ init_mv,
                                                  float* __restrict__ R) {
    __shared__ float Sb[MM * 64];            // 12.8 KB boundary states
    __shared__ float Rp[8 * CLEN * 64];      // 51.2 KB rd partials (mh=0)
    int b   = blockIdx.x >> 1;
    int vh  = blockIdx.x & 1;
    int tid = threadIdx.x;
    int lane = tid & 63;
    int wave = tid >> 6;               // 0..15
    int tc = wave >> 1;                // 0..7
    int mh = wave & 1;                 // 0..1 (wave-uniform)
    int v  = vh * 64 + lane;
    int t0 = tc * CLEN;
    int mbase = mh * MH;

    const float* wbase = w_pad + ((long)b * SS + t0) * WROW;
    const float* eab   = EA + (((long)b * SS + t0) * DVV + v) * 2;
    float*       Rb    = R + ((long)b * SS + t0) * DVV + v;

    // ---- pass 1: compose chunk affine map for this thread's 25 m-slots ----
    float A[MH], Bc[MH];
#pragma unroll
    for (int j = 0; j < MH; j++) { A[j] = 1.f; Bc[j] = 0.f; }

    float  w_cur  = wbase[lane];
    float2 ea_cur = *(const float2*)eab;
#pragma unroll 1
    for (int t = 0; t < CLEN; t++) {
        int tp = (t + 1 < CLEN) ? t + 1 : t;
        float  w_nxt  = wbase[tp * WROW + lane];
        float2 ea_nxt = *(const float2*)(eab + (long)tp * DVV * 2);
        float e = ea_cur.x, a = ea_cur.y;
#pragma unroll
        for (int j = 0; j < MH; j++) {
            float wm = rlane(w_cur, mbase + j);
            float alpha = fmaf(-wm, e, 1.f);
            A[j] *= alpha;
            Bc[j] = fmaf(alpha, Bc[j], wm * a);
        }
        w_cur = w_nxt; ea_cur = ea_nxt;
    }

    // ---- combine: serial over t-chunks; both m-halves in parallel ----
    float Mv[MH];
    if (tc == 0) {
#pragma unroll
        for (int j = 0; j < MH; j++) Mv[j] = init_mv[(mbase + j) * DVV + v];
#pragma unroll
        for (int j = 0; j < MH; j++) Sb[(mbase + j) * 64 + lane] = fmaf(A[j], Mv[j], Bc[j]);
    }
    __syncthreads();
    for (int c = 1; c < 8; c++) {
        if (tc == c) {
#pragma unroll
            for (int j = 0; j < MH; j++) Mv[j] = Sb[(mbase + j) * 64 + lane];
            if (c < 7) {
#pragma unroll
                for (int j = 0; j < MH; j++) Sb[(mbase + j) * 64 + lane] = fmaf(A[j], Mv[j], Bc[j]);
            }
        }
        __syncthreads();
    }

    // ---- pass 2: replay chunk; rd halves combine via LDS ----
    w_cur  = wbase[lane];
    ea_cur = *(const float2*)eab;
    float rdbuf[CLEN];
#pragma unroll 1
    for (int t = 0; t < CLEN; t++) {
        int tp = (t + 1 < CLEN) ? t + 1 : t;
        float  w_nxt  = wbase[tp * WROW + lane];
        float2 ea_nxt = *(const float2*)(eab + (long)tp * DVV * 2);
        float e = ea_cur.x, a = ea_cur.y;
        float rd = 0.f;
#pragma unroll
        for (int j = 0; j < MH; j++) {
            float wm = rlane(w_cur, mbase + j);
            rd = fmaf(wm, Mv[j], rd);                // read uses PRE-update Mv
            float alpha = fmaf(-wm, e, 1.f);
            Mv[j] = fmaf(alpha, Mv[j], wm * a);
        }
        if (mh == 0) Rp[(tc * CLEN + t) * 64 + lane] = rd;
        else         rdbuf[t] = rd;
        w_cur = w_nxt; ea_cur = ea_nxt;
    }
    __syncthreads();
    if (mh == 1) {
#pragma unroll
        for (int t = 0; t < CLEN; t++)
            Rb[t * DVV] = rdbuf[t] + Rp[(tc * CLEN + t) * 64 + lane];
    }
}

// ---------------- Kernel 4: FC head + BCE — NO global atomics ----------------
__global__ __launch_bounds__(256) void k_fc(const float* __restrict__ Rr,
                                            const int* __restrict__ q_data,
                                            const float* __restrict__ q_embed_w,
                                            const float* __restrict__ read_w,
                                            const float* __restrict__ read_b,
                                            const float* __restrict__ pred_w,
                                            const float* __restrict__ pred_b,
                                            const float* __restrict__ target,
                                            float* __restrict__ out,
                                            float2* __restrict__ part) {
    __shared__ float Wl[64 * 196];   // 50.2 KB
    __shared__ float xl[64 * 100];   // 25.6 KB
    __shared__ float2 red[4];
    int tid = threadIdx.x;
    int r0 = blockIdx.x * 64;
    int fq = tid & 15;
    int rh = tid >> 4;   // 0..15

    for (int i = tid; i < 3072; i += 256) {
        int f = i / 48, p = i - f * 48;
        *(float4*)(Wl + f * 196 + p * 4) = *(const float4*)(read_w + f * 192 + p * 4);
    }

    float accv[4][4];
#pragma unroll
    for (int i = 0; i < 4; i++)
#pragma unroll
        for (int j = 0; j < 4; j++) accv[i][j] = 0.f;

    for (int kc = 0; kc < 2; kc++) {
        __syncthreads();
        for (int i = tid; i < 1536; i += 256) {
            int r = i / 24, p = i - r * 24;
            float4 val;
            if (kc == 0) {
                val = *(const float4*)(Rr + (long)(r0 + r) * DVV + p * 4);
            } else if (p < 8) {
                val = *(const float4*)(Rr + (long)(r0 + r) * DVV + 96 + p * 4);
            } else {
                int qi = q_data[r0 + r];
                val = *(const float4*)(q_embed_w + (long)qi * DKK + (p - 8) * 4);
            }
            *(float4*)(xl + r * 100 + p * 4) = val;
        }
        __syncthreads();
#pragma unroll 4
        for (int kk = 0; kk < 96; kk += 4) {
            float4 wv[4], x4[4];
#pragma unroll
            for (int i = 0; i < 4; i++)
                wv[i] = *(const float4*)(Wl + (fq + 16 * i) * 196 + kc * 96 + kk);
#pragma unroll
            for (int j = 0; j < 4; j++)
                x4[j] = *(const float4*)(xl + (rh * 4 + j) * 100 + kk);
#pragma unroll
            for (int i = 0; i < 4; i++)
#pragma unroll
                for (int j = 0; j < 4; j++) {
                    accv[i][j] = fmaf(x4[j].x, wv[i].x, accv[i][j]);
                    accv[i][j] = fmaf(x4[j].y, wv[i].y, accv[i][j]);
                    accv[i][j] = fmaf(x4[j].z, wv[i].z, accv[i][j]);
                    accv[i][j] = fmaf(x4[j].w, wv[i].w, accv[i][j]);
                }
        }
    }

    float pb = pred_b[0];
    float rb_[4], pw_[4];
#pragma unroll
    for (int i = 0; i < 4; i++) { rb_[i] = read_b[fq + 16 * i]; pw_[i] = pred_w[fq + 16 * i]; }

    float bce_sum = 0.f, cnt = 0.f;
#pragma unroll
    for (int j = 0; j < 4; j++) {
        float pv = 0.f;
#pragma unroll
        for (int i = 0; i < 4; i++)
            pv = fmaf(pw_[i], tanhf(accv[i][j] + rb_[i]), pv);
        pv += __shfl_xor(pv, 1, 64);
        pv += __shfl_xor(pv, 2, 64);
        pv += __shfl_xor(pv, 4, 64);
        pv += __shfl_xor(pv, 8, 64);
        if (fq == 0) {
            int row = r0 + rh * 4 + j;
            float tgt = target[row];
            float logit = pv + pb;
            float prob = 0.f;
            if (tgt >= 0.f) {
                prob = 1.f / (1.f + expf(-logit));
                float bce = fmaxf(logit, 0.f) - logit * tgt + log1pf(expf(-fabsf(logit)));
                bce_sum += bce;
                cnt += 1.f;
            }
            out[1 + row] = prob;
        }
    }
    bce_sum += __shfl_xor(bce_sum, 16, 64);
    bce_sum += __shfl_xor(bce_sum, 32, 64);
    cnt     += __shfl_xor(cnt, 16, 64);
    cnt     += __shfl_xor(cnt, 32, 64);
    int lane = tid & 63, wid = tid >> 6;
    if (lane == 0) { red[wid].x = bce_sum; red[wid].y = cnt; }
    __syncthreads();
    if (tid == 0) {
        float2 p;
        p.x = red[0].x + red[1].x + red[2].x + red[3].x;
        p.y = red[0].y + red[1].y + red[2].y + red[3].y;
        part[blockIdx.x] = p;
    }
}

// ---------------- Kernel 5: reduce partials -> loss ----------------
__global__ __launch_bounds__(256) void k_loss(const float2* __restrict__ part,
                                              float* __restrict__ out) {
    __shared__ float2 red[4];
    int tid = threadIdx.x;
    float b = 0.f, c = 0.f;
    for (int i = tid; i < NFCB; i += 256) {
        float2 p = part[i];
        b += p.x; c += p.y;
    }
#pragma unroll
    for (int off = 32; off; off >>= 1) {
        b += __shfl_xor(b, off, 64);
        c += __shfl_xor(c, off, 64);
    }
    int lane = tid & 63, wid = tid >> 6;
    if (lane == 0) { red[wid].x = b; red[wid].y = c; }
    __syncthreads();
    if (tid == 0) {
        float B = red[0].x + red[1].x + red[2].x + red[3].x;
        float C = red[0].y + red[1].y + red[2].y + red[3].y;
        out[0] = B / fmaxf(C, 1.f);
    }
}

extern "C" void kernel_launch(void* const* d_in, const int* in_sizes, int n_in,
                              void* d_out, int out_size, void* d_ws, size_t ws_size,
                              hipStream_t stream) {
    const int*   q_data     = (const int*)d_in[0];
    const int*   qa_data    = (const int*)d_in[1];
    const float* target     = (const float*)d_in[2];
    const float* q_embed_w  = (const float*)d_in[3];
    const float* qa_embed_w = (const float*)d_in[4];
    const float* mem_key    = (const float*)d_in[5];
    const float* init_mv    = (const float*)d_in[6];
    const float* erase_w    = (const float*)d_in[7];
    const float* erase_b    = (const float*)d_in[8];
    const float* add_w      = (const float*)d_in[9];
    const float* add_b      = (const float*)d_in[10];
    const float* read_w     = (const float*)d_in[11];
    const float* read_b     = (const float*)d_in[12];
    const float* pred_w     = (const float*)d_in[13];
    const float* pred_b     = (const float*)d_in[14];
    float* out = (float*)d_out;
    float* ws  = (float*)d_ws;

    float*  w_all = ws + W_OFF;
    float*  EA    = ws + EA_OFF;
    float*  R     = ws + R_OFF;
    float2* part  = (float2*)(ws + ACC_OFF);

    k_scores<<<NROW / 128, 128, 0, stream>>>(q_data, q_embed_w, mem_key, w_all);
    k_ea<<<NROW / 64, 256, 0, stream>>>(qa_data, qa_embed_w, erase_w, erase_b,
                                        add_w, add_b, EA);
    k_scan<<<BB * 2, 1024, 0, stream>>>(w_all, EA, init_mv, R);
    k_fc<<<NFCB, 256, 0, stream>>>(R, q_data, q_embed_w, read_w, read_b,
                                   pred_w, pred_b, target, out, part);
    k_loss<<<1, 256, 0, stream>>>(part, out);
}

// Round 11
// 203.563 us; speedup vs baseline: 1.2732x; 1.2123x over previous
//
#include <hip/hip_runtime.h>
#include <math.h>

#define BB 128
#define SS 200
#define MM 50
#define DKK 64
#define DVV 128
#define FF 64
#define NROW (BB*SS)   // 25600

// w padded layout: direct m index, 64 floats/row, m in [0,50) valid, rest zero
#define WROW 64
#define NFCB (NROW/64) // 400 k_fc blocks
#define WLDS 136       // k_ea LDS bf16 row stride (128 + 8 pad -> 2-way bank alias, free)
#define CLEN 25        // scan: steps per chunk (8 chunks x 25 = 200)
#define MP 25          // scan: m-pairs per thread (50 m as 25 float2)

// workspace layout (floats)
#define W_OFF   0L
#define EA_OFF  (W_OFF + (long)NROW*WROW)        // interleaved (e,a) float2
#define R_OFF   (EA_OFF + (long)NROW*DVV*2)
#define ACC_OFF (R_OFF + (long)NROW*DVV)         // NFCB float2 partials

typedef __attribute__((ext_vector_type(8))) short bf16x8;   // 8 bf16 (4 VGPRs)
typedef __attribute__((ext_vector_type(4))) float f32x4;
typedef __attribute__((ext_vector_type(2))) float f32x2;    // -> v_pk_*_f32

__device__ __forceinline__ float rlane(float v, int l) {
    return __builtin_bit_cast(float, __builtin_amdgcn_readlane(__builtin_bit_cast(unsigned, v), l));
}
__device__ __forceinline__ short f2bf(float f) {   // RNE fp32->bf16
    unsigned u = __builtin_bit_cast(unsigned, f);
    u += 0x7fff + ((u >> 16) & 1);
    return (short)(u >> 16);
}

// ---------------- Kernel 1: w = softmax(q_e @ mem_key^T) ----------------
__global__ __launch_bounds__(128) void k_scores(const int* __restrict__ q_data,
                                                const float* __restrict__ q_embed_w,
                                                const float* __restrict__ mem_key,
                                                float* __restrict__ w_out) {
    __shared__ float4 mk[MM * 16];   // 12.8 KB
    int tid = threadIdx.x;
    const float4* mkg = (const float4*)mem_key;
    for (int i = tid; i < MM * 16; i += 128) mk[i] = mkg[i];
    __syncthreads();

    int item = blockIdx.x * 128 + tid;
    int qidx = q_data[item];
    const float4* qg = (const float4*)(q_embed_w + (long)qidx * DKK);
    float4 q[16];
#pragma unroll
    for (int i = 0; i < 16; i++) q[i] = qg[i];

    float s[MM];
    float mx = -1e30f;
#pragma unroll 2
    for (int m = 0; m < MM; m++) {
        float a = 0.f;
#pragma unroll
        for (int k4 = 0; k4 < 16; k4++) {
            float4 mkv = mk[m * 16 + k4];
            float4 qv = q[k4];
            a = fmaf(qv.x, mkv.x, a);
            a = fmaf(qv.y, mkv.y, a);
            a = fmaf(qv.z, mkv.z, a);
            a = fmaf(qv.w, mkv.w, a);
        }
        s[m] = a;
        mx = fmaxf(mx, a);
    }
    float sum = 0.f;
#pragma unroll
    for (int m = 0; m < MM; m++) { s[m] = expf(s[m] - mx); sum += s[m]; }
    float inv = 1.f / sum;

    float* wo = w_out + (long)item * WROW;
#pragma unroll
    for (int m = 0; m < MM; m++) wo[m] = s[m] * inv;
#pragma unroll
    for (int m = MM; m < WROW; m++) wo[m] = 0.f;
}

// ---------------- Kernel 2: e/a GEMM via bf16 MFMA ----------------
__global__ __launch_bounds__(256) void k_ea(const int* __restrict__ qa_data,
                                            const float* __restrict__ qa_embed_w,
                                            const float* __restrict__ erase_w,
                                            const float* __restrict__ erase_b,
                                            const float* __restrict__ add_w,
                                            const float* __restrict__ add_b,
                                            float* __restrict__ EA) {
    __shared__ short Wl[2 * 128 * WLDS];   // 69.6 KB
    int tid = threadIdx.x;
    int r0 = blockIdx.x * 64;
    int lane = tid & 63;
    int wv = tid >> 6;          // wave 0..3
    int n = lane & 15;
    int quad = lane >> 4;       // 0..3

    for (int i = tid; i < 8192; i += 256) {
        int mat = i >> 12;
        int r = (i >> 5) & 127;
        int p = i & 31;
        float4 src = *(const float4*)((mat ? add_w : erase_w) + r * 128 + p * 4);
        short4 d;
        d.x = f2bf(src.x); d.y = f2bf(src.y); d.z = f2bf(src.z); d.w = f2bf(src.w);
        *(short4*)(Wl + (mat * 128 + r) * WLDS + p * 4) = d;
    }

    int arow = r0 + wv * 16 + n;
    int qidx = qa_data[arow];
    const float* qp = qa_embed_w + (long)qidx * DVV + quad * 8;
    bf16x8 afrag[4];
#pragma unroll
    for (int kb = 0; kb < 4; kb++) {
        float4 lo = *(const float4*)(qp + kb * 32);
        float4 hi = *(const float4*)(qp + kb * 32 + 4);
        bf16x8 f;
        f[0] = f2bf(lo.x); f[1] = f2bf(lo.y); f[2] = f2bf(lo.z); f[3] = f2bf(lo.w);
        f[4] = f2bf(hi.x); f[5] = f2bf(hi.y); f[6] = f2bf(hi.z); f[7] = f2bf(hi.w);
        afrag[kb] = f;
    }

    float eb_[8], ab_[8];
#pragma unroll
    for (int vt = 0; vt < 8; vt++) {
        eb_[vt] = erase_b[vt * 16 + n];
        ab_[vt] = add_b[vt * 16 + n];
    }
    __syncthreads();

    int rowbase = r0 + wv * 16 + quad * 4;
#pragma unroll 2
    for (int vt = 0; vt < 8; vt++) {
        int vrow = vt * 16 + n;
        f32x4 ae = {0.f, 0.f, 0.f, 0.f};
        f32x4 aa = {0.f, 0.f, 0.f, 0.f};
#pragma unroll
        for (int kb = 0; kb < 4; kb++) {
            bf16x8 be = *(const bf16x8*)(Wl + vrow * WLDS + kb * 32 + quad * 8);
            bf16x8 ba = *(const bf16x8*)(Wl + (128 + vrow) * WLDS + kb * 32 + quad * 8);
            ae = __builtin_amdgcn_mfma_f32_16x16x32_bf16(afrag[kb], be, ae, 0, 0, 0);
            aa = __builtin_amdgcn_mfma_f32_16x16x32_bf16(afrag[kb], ba, aa, 0, 0, 0);
        }
        int v = vt * 16 + n;
        float eb = eb_[vt], ab = ab_[vt];
#pragma unroll
        for (int r = 0; r < 4; r++) {
            float ev = 1.f / (1.f + __expf(-(ae[r] + eb)));
            float av = 2.f / (1.f + __expf(-2.f * (aa[r] + ab))) - 1.f;
            float2 o; o.x = ev; o.y = av;
            *(float2*)(EA + (((long)(rowbase + r)) * DVV + v) * 2) = o;
        }
    }
}

// ---------------- Kernel 3: chunked affine scan — R8 structure + packed fp32 ----------------
// Block = (b, v_half): 8 waves = 8 chunks of 25 steps; lane = v; all 50 m in-thread
// as 25 float2 pairs -> v_pk_fma_f32. w broadcast via readlane (const lane idx).
// Combine: 7 LDS rounds. (512,2) bounds -> allocator free to use VGPR+AGPR, no spill.
__global__ __launch_bounds__(512, 2) void k_scan(const float* __restrict__ w_pad,
                                                 const float* __restrict__ EA,
                                                 const float* __restrict__ init_mv,
                                                 float* __restrict__ R) {
    __shared__ float Sb[MM * 64];      // 12.8 KB boundary state
    int b   = blockIdx.x >> 1;
    int vh  = blockIdx.x & 1;
    int tid = threadIdx.x;
    int lane  = tid & 63;
    int chunk = tid >> 6;              // wave id = chunk (0..7)
    int v  = vh * 64 + lane;
    int t0 = chunk * CLEN;

    const float* wbase = w_pad + ((long)b * SS + t0) * WROW;
    const float* eab   = EA + (((long)b * SS + t0) * DVV + v) * 2;
    float*       Rb    = R + ((long)b * SS + t0) * DVV + v;

    const f32x2 one = {1.f, 1.f};

    // ---- pass 1: compose the chunk's affine map per m-pair ----
    f32x2 A2[MP], B2[MP];
#pragma unroll
    for (int j = 0; j < MP; j++) { A2[j] = one; B2[j] = (f32x2){0.f, 0.f}; }

    float  w_cur  = wbase[lane];
    float2 ea_cur = *(const float2*)eab;
#pragma unroll 1
    for (int t = 0; t < CLEN; t++) {
        int tp = (t + 1 < CLEN) ? t + 1 : t;
        float  w_nxt  = wbase[tp * WROW + lane];
        float2 ea_nxt = *(const float2*)(eab + (long)tp * DVV * 2);
        f32x2 e2 = {ea_cur.x, ea_cur.x};
        f32x2 a2 = {ea_cur.y, ea_cur.y};
#pragma unroll
        for (int j = 0; j < MP; j++) {
            f32x2 w2 = {rlane(w_cur, 2 * j), rlane(w_cur, 2 * j + 1)};
            f32x2 alpha = one - w2 * e2;          // v_pk_fma
            A2[j] = A2[j] * alpha;                // v_pk_mul
            B2[j] = alpha * B2[j] + w2 * a2;      // 2x v_pk_fma
        }
        w_cur = w_nxt; ea_cur = ea_nxt;
    }

    // ---- combine: sequential over chunks through LDS ----
    f32x2 Mv[MP];
    if (chunk == 0) {
#pragma unroll
        for (int j = 0; j < MP; j++) {
            Mv[j].x = init_mv[(2 * j) * DVV + v];
            Mv[j].y = init_mv[(2 * j + 1) * DVV + v];
        }
#pragma unroll
        for (int j = 0; j < MP; j++) {
            f32x2 nb = A2[j] * Mv[j] + B2[j];
            Sb[(2 * j) * 64 + lane] = nb.x;
            Sb[(2 * j + 1) * 64 + lane] = nb.y;
        }
    }
    __syncthreads();
    for (int c = 1; c < 8; c++) {
        if (chunk == c) {
#pragma unroll
            for (int j = 0; j < MP; j++) {
                Mv[j].x = Sb[(2 * j) * 64 + lane];
                Mv[j].y = Sb[(2 * j + 1) * 64 + lane];
            }
            if (c < 7) {
#pragma unroll
                for (int j = 0; j < MP; j++) {
                    f32x2 nb = A2[j] * Mv[j] + B2[j];
                    Sb[(2 * j) * 64 + lane] = nb.x;
                    Sb[(2 * j + 1) * 64 + lane] = nb.y;
                }
            }
        }
        __syncthreads();
    }

    // ---- pass 2: replay chunk, emitting reads (pre-update Mv) ----
    w_cur  = wbase[lane];
    ea_cur = *(const float2*)eab;
#pragma unroll 1
    for (int t = 0; t < CLEN; t++) {
        int tp = (t + 1 < CLEN) ? t + 1 : t;
        float  w_nxt  = wbase[tp * WROW + lane];
        float2 ea_nxt = *(const float2*)(eab + (long)tp * DVV * 2);
        f32x2 e2 = {ea_cur.x, ea_cur.x};
        f32x2 a2 = {ea_cur.y, ea_cur.y};
        f32x2 rd2 = {0.f, 0.f};
#pragma unroll
        for (int j = 0; j < MP; j++) {
            f32x2 w2 = {rlane(w_cur, 2 * j), rlane(w_cur, 2 * j + 1)};
            rd2 = rd2 + w2 * Mv[j];               // read uses PRE-update Mv
            f32x2 alpha = one - w2 * e2;
            Mv[j] = alpha * Mv[j] + w2 * a2;
        }
        Rb[t * DVV] = rd2.x + rd2.y;
        w_cur = w_nxt; ea_cur = ea_nxt;
    }
}

// ---------------- Kernel 4: FC head + BCE — NO global atomics ----------------
__global__ __launch_bounds__(256) void k_fc(const float* __restrict__ Rr,
                                            const int* __restrict__ q_data,
                                            const float* __restrict__ q_embed_w,
                                            const float* __restrict__ read_w,
                                            const float* __restrict__ read_b,
                                            const float* __restrict__ pred_w,
                                            const float* __restrict__ pred_b,
                                            const float* __restrict__ target,
                                            float* __restrict__ out,
                                            float2* __restrict__ part) {
    __shared__ float Wl[64 * 196];   // 50.2 KB
    __shared__ float xl[64 * 100];   // 25.6 KB
    __shared__ float2 red[4];
    int tid = threadIdx.x;
    int r0 = blockIdx.x * 64;
    int fq = tid & 15;
    int rh = tid >> 4;   // 0..15

    for (int i = tid; i < 3072; i += 256) {
        int f = i / 48, p = i - f * 48;
        *(float4*)(Wl + f * 196 + p * 4) = *(const float4*)(read_w + f * 192 + p * 4);
    }

    float accv[4][4];
#pragma unroll
    for (int i = 0; i < 4; i++)
#pragma unroll
        for (int j = 0; j < 4; j++) accv[i][j] = 0.f;

    for (int kc = 0; kc < 2; kc++) {
        __syncthreads();
        for (int i = tid; i < 1536; i += 256) {
            int r = i / 24, p = i - r * 24;
            float4 val;
            if (kc == 0) {
                val = *(const float4*)(Rr + (long)(r0 + r) * DVV + p * 4);
            } else if (p < 8) {
                val = *(const float4*)(Rr + (long)(r0 + r) * DVV + 96 + p * 4);
            } else {
                int qi = q_data[r0 + r];
                val = *(const float4*)(q_embed_w + (long)qi * DKK + (p - 8) * 4);
            }
            *(float4*)(xl + r * 100 + p * 4) = val;
        }
        __syncthreads();
#pragma unroll 4
        for (int kk = 0; kk < 96; kk += 4) {
            float4 wv[4], x4[4];
#pragma unroll
            for (int i = 0; i < 4; i++)
                wv[i] = *(const float4*)(Wl + (fq + 16 * i) * 196 + kc * 96 + kk);
#pragma unroll
            for (int j = 0; j < 4; j++)
                x4[j] = *(const float4*)(xl + (rh * 4 + j) * 100 + kk);
#pragma unroll
            for (int i = 0; i < 4; i++)
#pragma unroll
                for (int j = 0; j < 4; j++) {
                    accv[i][j] = fmaf(x4[j].x, wv[i].x, accv[i][j]);
                    accv[i][j] = fmaf(x4[j].y, wv[i].y, accv[i][j]);
                    accv[i][j] = fmaf(x4[j].z, wv[i].z, accv[i][j]);
                    accv[i][j] = fmaf(x4[j].w, wv[i].w, accv[i][j]);
                }
        }
    }

    float pb = pred_b[0];
    float rb_[4], pw_[4];
#pragma unroll
    for (int i = 0; i < 4; i++) { rb_[i] = read_b[fq + 16 * i]; pw_[i] = pred_w[fq + 16 * i]; }

    float bce_sum = 0.f, cnt = 0.f;
#pragma unroll
    for (int j = 0; j < 4; j++) {
        float pv = 0.f;
#pragma unroll
        for (int i = 0; i < 4; i++)
            pv = fmaf(pw_[i], tanhf(accv[i][j] + rb_[i]), pv);
        pv += __shfl_xor(pv, 1, 64);
        pv += __shfl_xor(pv, 2, 64);
        pv += __shfl_xor(pv, 4, 64);
        pv += __shfl_xor(pv, 8, 64);
        if (fq == 0) {
            int row = r0 + rh * 4 + j;
            float tgt = target[row];
            float logit = pv + pb;
            float prob = 0.f;
            if (tgt >= 0.f) {
                prob = 1.f / (1.f + expf(-logit));
                float bce = fmaxf(logit, 0.f) - logit * tgt + log1pf(expf(-fabsf(logit)));
                bce_sum += bce;
                cnt += 1.f;
            }
            out[1 + row] = prob;
        }
    }
    bce_sum += __shfl_xor(bce_sum, 16, 64);
    bce_sum += __shfl_xor(bce_sum, 32, 64);
    cnt     += __shfl_xor(cnt, 16, 64);
    cnt     += __shfl_xor(cnt, 32, 64);
    int lane = tid & 63, wid = tid >> 6;
    if (lane == 0) { red[wid].x = bce_sum; red[wid].y = cnt; }
    __syncthreads();
    if (tid == 0) {
        float2 p;
        p.x = red[0].x + red[1].x + red[2].x + red[3].x;
        p.y = red[0].y + red[1].y + red[2].y + red[3].y;
        part[blockIdx.x] = p;
    }
}

// ---------------- Kernel 5: reduce partials -> loss ----------------
__global__ __launch_bounds__(256) void k_loss(const float2* __restrict__ part,
                                              float* __restrict__ out) {
    __shared__ float2 red[4];
    int tid = threadIdx.x;
    float b = 0.f, c = 0.f;
    for (int i = tid; i < NFCB; i += 256) {
        float2 p = part[i];
        b += p.x; c += p.y;
    }
#pragma unroll
    for (int off = 32; off; off >>= 1) {
        b += __shfl_xor(b, off, 64);
        c += __shfl_xor(c, off, 64);
    }
    int lane = tid & 63, wid = tid >> 6;
    if (lane == 0) { red[wid].x = b; red[wid].y = c; }
    __syncthreads();
    if (tid == 0) {
        float B = red[0].x + red[1].x + red[2].x + red[3].x;
        float C = red[0].y + red[1].y + red[2].y + red[3].y;
        out[0] = B / fmaxf(C, 1.f);
    }
}

extern "C" void kernel_launch(void* const* d_in, const int* in_sizes, int n_in,
                              void* d_out, int out_size, void* d_ws, size_t ws_size,
                              hipStream_t stream) {
    const int*   q_data     = (const int*)d_in[0];
    const int*   qa_data    = (const int*)d_in[1];
    const float* target     = (const float*)d_in[2];
    const float* q_embed_w  = (const float*)d_in[3];
    const float* qa_embed_w = (const float*)d_in[4];
    const float* mem_key    = (const float*)d_in[5];
    const float* init_mv    = (const float*)d_in[6];
    const float* erase_w    = (const float*)d_in[7];
    const float* erase_b    = (const float*)d_in[8];
    const float* add_w      = (const float*)d_in[9];
    const float* add_b      = (const float*)d_in[10];
    const float* read_w     = (const float*)d_in[11];
    const float* read_b     = (const float*)d_in[12];
    const float* pred_w     = (const float*)d_in[13];
    const float* pred_b     = (const float*)d_in[14];
    float* out = (float*)d_out;
    float* ws  = (float*)d_ws;

    float*  w_all = ws + W_OFF;
    float*  EA    = ws + EA_OFF;
    float*  R     = ws + R_OFF;
    float2* part  = (float2*)(ws + ACC_OFF);

    k_scores<<<NROW / 128, 128, 0, stream>>>(q_data, q_embed_w, mem_key, w_all);
    k_ea<<<NROW / 64, 256, 0, stream>>>(qa_data, qa_embed_w, erase_w, erase_b,
                                        add_w, add_b, EA);
    k_scan<<<BB * 2, 512, 0, stream>>>(w_all, EA, init_mv, R);
    k_fc<<<NFCB, 256, 0, stream>>>(R, q_data, q_embed_w, read_w, read_b,
                                   pred_w, pred_b, target, out, part);
    k_loss<<<1, 256, 0, stream>>>(part, out);
}

// Round 12
// 194.287 us; speedup vs baseline: 1.3340x; 1.0477x over previous
//
#include <hip/hip_runtime.h>
#include <math.h>

#define BB 128
#define SS 200
#define MM 50
#define DKK 64
#define DVV 128
#define FF 64
#define NROW (BB*SS)   // 25600

#define WROW 64        // w padded layout: 64 floats/row, m<50 valid, rest zero
#define NFCB (NROW/64) // 400 k_fc blocks
#define WLDS 136       // k_pre/ea LDS bf16 row stride (2-way bank alias = free)
#define CLEN 25        // scan: steps per chunk (8 chunks x 25 = 200)
#define MP 25          // scan: m-pairs per thread (50 m as 25 float2)
#define NSCB 100       // scores blocks inside k_pre (256 items each)

// workspace layout (floats)
#define W_OFF   0L
#define EA_OFF  (W_OFF + (long)NROW*WROW)        // interleaved (e,a) float2
#define R_OFF   (EA_OFF + (long)NROW*DVV*2)
#define ACC_OFF (R_OFF + (long)NROW*DVV)         // [0]=bce [1]=cnt [2]=counter bits

typedef __attribute__((ext_vector_type(8))) short bf16x8;   // 8 bf16 (4 VGPRs)
typedef __attribute__((ext_vector_type(4))) float f32x4;
typedef __attribute__((ext_vector_type(2))) float f32x2;    // -> v_pk_*_f32

__device__ __forceinline__ float rlane(float v, int l) {
    return __builtin_bit_cast(float, __builtin_amdgcn_readlane(__builtin_bit_cast(unsigned, v), l));
}
__device__ __forceinline__ short f2bf(float f) {   // RNE fp32->bf16
    unsigned u = __builtin_bit_cast(unsigned, f);
    u += 0x7fff + ((u >> 16) & 1);
    return (short)(u >> 16);
}

// ---------------- Kernel 1: fused scores + ea (independent block types) ----------------
// blocks [0,100): softmax(q_e@mem_key^T) -> w, 256 items/block; block 0 zeroes acc.
// blocks [100,500): e/a GEMM via bf16 MFMA, 64 rows/block.
__global__ __launch_bounds__(256) void k_pre(const int* __restrict__ q_data,
                                             const float* __restrict__ q_embed_w,
                                             const float* __restrict__ mem_key,
                                             const int* __restrict__ qa_data,
                                             const float* __restrict__ qa_embed_w,
                                             const float* __restrict__ erase_w,
                                             const float* __restrict__ erase_b,
                                             const float* __restrict__ add_w,
                                             const float* __restrict__ add_b,
                                             float* __restrict__ w_out,
                                             float* __restrict__ EA,
                                             float* __restrict__ acc) {
    __shared__ union {
        short  wl[2 * 128 * WLDS];   // ea branch: bf16 weights, 69.6 KB
        float4 mk[MM * 16];          // scores branch: mem_key, 12.8 KB
    } sh;
    int tid = threadIdx.x;
    int bid = blockIdx.x;

    if (bid < NSCB) {
        // ---------- scores branch ----------
        if (bid == 0 && tid == 0) {
            acc[0] = 0.f; acc[1] = 0.f;
            ((unsigned*)acc)[2] = 0u;
        }
        const float4* mkg = (const float4*)mem_key;
        for (int i = tid; i < MM * 16; i += 256) sh.mk[i] = mkg[i];
        __syncthreads();

        int item = bid * 256 + tid;
        int qidx = q_data[item];
        const float4* qg = (const float4*)(q_embed_w + (long)qidx * DKK);
        float4 q[16];
#pragma unroll
        for (int i = 0; i < 16; i++) q[i] = qg[i];

        float s[MM];
        float mx = -1e30f;
#pragma unroll 2
        for (int m = 0; m < MM; m++) {
            float a = 0.f;
#pragma unroll
            for (int k4 = 0; k4 < 16; k4++) {
                float4 mkv = sh.mk[m * 16 + k4];
                float4 qv = q[k4];
                a = fmaf(qv.x, mkv.x, a);
                a = fmaf(qv.y, mkv.y, a);
                a = fmaf(qv.z, mkv.z, a);
                a = fmaf(qv.w, mkv.w, a);
            }
            s[m] = a;
            mx = fmaxf(mx, a);
        }
        float sum = 0.f;
#pragma unroll
        for (int m = 0; m < MM; m++) { s[m] = expf(s[m] - mx); sum += s[m]; }
        float inv = 1.f / sum;

        float* wo = w_out + (long)item * WROW;
#pragma unroll
        for (int m = 0; m < MM; m++) wo[m] = s[m] * inv;
#pragma unroll
        for (int m = MM; m < WROW; m++) wo[m] = 0.f;
        return;
    }

    // ---------- ea branch ----------
    int r0 = (bid - NSCB) * 64;
    int lane = tid & 63;
    int wv = tid >> 6;          // wave 0..3
    int n = lane & 15;
    int quad = lane >> 4;       // 0..3

    for (int i = tid; i < 8192; i += 256) {
        int mat = i >> 12;
        int r = (i >> 5) & 127;
        int p = i & 31;
        float4 src = *(const float4*)((mat ? add_w : erase_w) + r * 128 + p * 4);
        short4 d;
        d.x = f2bf(src.x); d.y = f2bf(src.y); d.z = f2bf(src.z); d.w = f2bf(src.w);
        *(short4*)(sh.wl + (mat * 128 + r) * WLDS + p * 4) = d;
    }

    int arow = r0 + wv * 16 + n;
    int qidx = qa_data[arow];
    const float* qp = qa_embed_w + (long)qidx * DVV + quad * 8;
    bf16x8 afrag[4];
#pragma unroll
    for (int kb = 0; kb < 4; kb++) {
        float4 lo = *(const float4*)(qp + kb * 32);
        float4 hi = *(const float4*)(qp + kb * 32 + 4);
        bf16x8 f;
        f[0] = f2bf(lo.x); f[1] = f2bf(lo.y); f[2] = f2bf(lo.z); f[3] = f2bf(lo.w);
        f[4] = f2bf(hi.x); f[5] = f2bf(hi.y); f[6] = f2bf(hi.z); f[7] = f2bf(hi.w);
        afrag[kb] = f;
    }

    float eb_[8], ab_[8];
#pragma unroll
    for (int vt = 0; vt < 8; vt++) {
        eb_[vt] = erase_b[vt * 16 + n];
        ab_[vt] = add_b[vt * 16 + n];
    }
    __syncthreads();

    int rowbase = r0 + wv * 16 + quad * 4;
#pragma unroll 2
    for (int vt = 0; vt < 8; vt++) {
        int vrow = vt * 16 + n;
        f32x4 ae = {0.f, 0.f, 0.f, 0.f};
        f32x4 aa = {0.f, 0.f, 0.f, 0.f};
#pragma unroll
        for (int kb = 0; kb < 4; kb++) {
            bf16x8 be = *(const bf16x8*)(sh.wl + vrow * WLDS + kb * 32 + quad * 8);
            bf16x8 ba = *(const bf16x8*)(sh.wl + (128 + vrow) * WLDS + kb * 32 + quad * 8);
            ae = __builtin_amdgcn_mfma_f32_16x16x32_bf16(afrag[kb], be, ae, 0, 0, 0);
            aa = __builtin_amdgcn_mfma_f32_16x16x32_bf16(afrag[kb], ba, aa, 0, 0, 0);
        }
        int v = vt * 16 + n;
        float eb = eb_[vt], ab = ab_[vt];
#pragma unroll
        for (int r = 0; r < 4; r++) {
            float ev = 1.f / (1.f + __expf(-(ae[r] + eb)));
            float av = 2.f / (1.f + __expf(-2.f * (aa[r] + ab))) - 1.f;
            float2 o; o.x = ev; o.y = av;
            *(float2*)(EA + (((long)(rowbase + r)) * DVV + v) * 2) = o;
        }
    }
}

// ---------------- Kernel 2: chunked affine scan (unchanged, known-good) ----------------
__global__ __launch_bounds__(512, 2) void k_scan(const float* __restrict__ w_pad,
                                                 const float* __restrict__ EA,
                                                 const float* __restrict__ init_mv,
                                                 float* __restrict__ R) {
    __shared__ float Sb[MM * 64];      // 12.8 KB boundary state
    int b   = blockIdx.x >> 1;
    int vh  = blockIdx.x & 1;
    int tid = threadIdx.x;
    int lane  = tid & 63;
    int chunk = tid >> 6;              // wave id = chunk (0..7)
    int v  = vh * 64 + lane;
    int t0 = chunk * CLEN;

    const float* wbase = w_pad + ((long)b * SS + t0) * WROW;
    const float* eab   = EA + (((long)b * SS + t0) * DVV + v) * 2;
    float*       Rb    = R + ((long)b * SS + t0) * DVV + v;

    const f32x2 one = {1.f, 1.f};

    f32x2 A2[MP], B2[MP];
#pragma unroll
    for (int j = 0; j < MP; j++) { A2[j] = one; B2[j] = (f32x2){0.f, 0.f}; }

    float  w_cur  = wbase[lane];
    float2 ea_cur = *(const float2*)eab;
#pragma unroll 1
    for (int t = 0; t < CLEN; t++) {
        int tp = (t + 1 < CLEN) ? t + 1 : t;
        float  w_nxt  = wbase[tp * WROW + lane];
        float2 ea_nxt = *(const float2*)(eab + (long)tp * DVV * 2);
        f32x2 e2 = {ea_cur.x, ea_cur.x};
        f32x2 a2 = {ea_cur.y, ea_cur.y};
#pragma unroll
        for (int j = 0; j < MP; j++) {
            f32x2 w2 = {rlane(w_cur, 2 * j), rlane(w_cur, 2 * j + 1)};
            f32x2 alpha = one - w2 * e2;
            A2[j] = A2[j] * alpha;
            B2[j] = alpha * B2[j] + w2 * a2;
        }
        w_cur = w_nxt; ea_cur = ea_nxt;
    }

    f32x2 Mv[MP];
    if (chunk == 0) {
#pragma unroll
        for (int j = 0; j < MP; j++) {
            Mv[j].x = init_mv[(2 * j) * DVV + v];
            Mv[j].y = init_mv[(2 * j + 1) * DVV + v];
        }
#pragma unroll
        for (int j = 0; j < MP; j++) {
            f32x2 nb = A2[j] * Mv[j] + B2[j];
            Sb[(2 * j) * 64 + lane] = nb.x;
            Sb[(2 * j + 1) * 64 + lane] = nb.y;
        }
    }
    __syncthreads();
    for (int c = 1; c < 8; c++) {
        if (chunk == c) {
#pragma unroll
            for (int j = 0; j < MP; j++) {
                Mv[j].x = Sb[(2 * j) * 64 + lane];
                Mv[j].y = Sb[(2 * j + 1) * 64 + lane];
            }
            if (c < 7) {
#pragma unroll
                for (int j = 0; j < MP; j++) {
                    f32x2 nb = A2[j] * Mv[j] + B2[j];
                    Sb[(2 * j) * 64 + lane] = nb.x;
                    Sb[(2 * j + 1) * 64 + lane] = nb.y;
                }
            }
        }
        __syncthreads();
    }

    w_cur  = wbase[lane];
    ea_cur = *(const float2*)eab;
#pragma unroll 1
    for (int t = 0; t < CLEN; t++) {
        int tp = (t + 1 < CLEN) ? t + 1 : t;
        float  w_nxt  = wbase[tp * WROW + lane];
        float2 ea_nxt = *(const float2*)(eab + (long)tp * DVV * 2);
        f32x2 e2 = {ea_cur.x, ea_cur.x};
        f32x2 a2 = {ea_cur.y, ea_cur.y};
        f32x2 rd2 = {0.f, 0.f};
#pragma unroll
        for (int j = 0; j < MP; j++) {
            f32x2 w2 = {rlane(w_cur, 2 * j), rlane(w_cur, 2 * j + 1)};
            rd2 = rd2 + w2 * Mv[j];
            f32x2 alpha = one - w2 * e2;
            Mv[j] = alpha * Mv[j] + w2 * a2;
        }
        Rb[t * DVV] = rd2.x + rd2.y;
        w_cur = w_nxt; ea_cur = ea_nxt;
    }
}

// ---------------- Kernel 3: FC head + BCE + fused loss (last-block pattern) ----------------
__global__ __launch_bounds__(256) void k_fc(const float* __restrict__ Rr,
                                            const int* __restrict__ q_data,
                                            const float* __restrict__ q_embed_w,
                                            const float* __restrict__ read_w,
                                            const float* __restrict__ read_b,
                                            const float* __restrict__ pred_w,
                                            const float* __restrict__ pred_b,
                                            const float* __restrict__ target,
                                            float* __restrict__ out,
                                            float* __restrict__ acc) {
    __shared__ float Wl[64 * 196];   // 50.2 KB
    __shared__ float xl[64 * 100];   // 25.6 KB
    __shared__ float2 red[4];
    int tid = threadIdx.x;
    int r0 = blockIdx.x * 64;
    int fq = tid & 15;
    int rh = tid >> 4;   // 0..15

    for (int i = tid; i < 3072; i += 256) {
        int f = i / 48, p = i - f * 48;
        *(float4*)(Wl + f * 196 + p * 4) = *(const float4*)(read_w + f * 192 + p * 4);
    }

    float accv[4][4];
#pragma unroll
    for (int i = 0; i < 4; i++)
#pragma unroll
        for (int j = 0; j < 4; j++) accv[i][j] = 0.f;

    for (int kc = 0; kc < 2; kc++) {
        __syncthreads();
        for (int i = tid; i < 1536; i += 256) {
            int r = i / 24, p = i - r * 24;
            float4 val;
            if (kc == 0) {
                val = *(const float4*)(Rr + (long)(r0 + r) * DVV + p * 4);
            } else if (p < 8) {
                val = *(const float4*)(Rr + (long)(r0 + r) * DVV + 96 + p * 4);
            } else {
                int qi = q_data[r0 + r];
                val = *(const float4*)(q_embed_w + (long)qi * DKK + (p - 8) * 4);
            }
            *(float4*)(xl + r * 100 + p * 4) = val;
        }
        __syncthreads();
#pragma unroll 4
        for (int kk = 0; kk < 96; kk += 4) {
            float4 wv[4], x4[4];
#pragma unroll
            for (int i = 0; i < 4; i++)
                wv[i] = *(const float4*)(Wl + (fq + 16 * i) * 196 + kc * 96 + kk);
#pragma unroll
            for (int j = 0; j < 4; j++)
                x4[j] = *(const float4*)(xl + (rh * 4 + j) * 100 + kk);
#pragma unroll
            for (int i = 0; i < 4; i++)
#pragma unroll
                for (int j = 0; j < 4; j++) {
                    accv[i][j] = fmaf(x4[j].x, wv[i].x, accv[i][j]);
                    accv[i][j] = fmaf(x4[j].y, wv[i].y, accv[i][j]);
                    accv[i][j] = fmaf(x4[j].z, wv[i].z, accv[i][j]);
                    accv[i][j] = fmaf(x4[j].w, wv[i].w, accv[i][j]);
                }
        }
    }

    float pb = pred_b[0];
    float rb_[4], pw_[4];
#pragma unroll
    for (int i = 0; i < 4; i++) { rb_[i] = read_b[fq + 16 * i]; pw_[i] = pred_w[fq + 16 * i]; }

    float bce_sum = 0.f, cnt = 0.f;
#pragma unroll
    for (int j = 0; j < 4; j++) {
        float pv = 0.f;
#pragma unroll
        for (int i = 0; i < 4; i++)
            pv = fmaf(pw_[i], tanhf(accv[i][j] + rb_[i]), pv);
        pv += __shfl_xor(pv, 1, 64);
        pv += __shfl_xor(pv, 2, 64);
        pv += __shfl_xor(pv, 4, 64);
        pv += __shfl_xor(pv, 8, 64);
        if (fq == 0) {
            int row = r0 + rh * 4 + j;
            float tgt = target[row];
            float logit = pv + pb;
            float prob = 0.f;
            if (tgt >= 0.f) {
                prob = 1.f / (1.f + expf(-logit));
                float bce = fmaxf(logit, 0.f) - logit * tgt + log1pf(expf(-fabsf(logit)));
                bce_sum += bce;
                cnt += 1.f;
            }
            out[1 + row] = prob;
        }
    }
    bce_sum += __shfl_xor(bce_sum, 16, 64);
    bce_sum += __shfl_xor(bce_sum, 32, 64);
    cnt     += __shfl_xor(cnt, 16, 64);
    cnt     += __shfl_xor(cnt, 32, 64);
    int lane = tid & 63, wid = tid >> 6;
    if (lane == 0) { red[wid].x = bce_sum; red[wid].y = cnt; }
    __syncthreads();
    if (tid == 0) {
        float bsum = red[0].x + red[1].x + red[2].x + red[3].x;
        float csum = red[0].y + red[1].y + red[2].y + red[3].y;
        atomicAdd(&acc[0], bsum);
        atomicAdd(&acc[1], csum);
        __threadfence();
        unsigned prev = atomicAdd((unsigned*)acc + 2, 1u);
        if (prev == NFCB - 1) {          // last block computes the loss
            __threadfence();
            float B = atomicAdd(&acc[0], 0.f);
            float C = atomicAdd(&acc[1], 0.f);
            out[0] = B / fmaxf(C, 1.f);
        }
    }
}

extern "C" void kernel_launch(void* const* d_in, const int* in_sizes, int n_in,
                              void* d_out, int out_size, void* d_ws, size_t ws_size,
                              hipStream_t stream) {
    const int*   q_data     = (const int*)d_in[0];
    const int*   qa_data    = (const int*)d_in[1];
    const float* target     = (const float*)d_in[2];
    const float* q_embed_w  = (const float*)d_in[3];
    const float* qa_embed_w = (const float*)d_in[4];
    const float* mem_key    = (const float*)d_in[5];
    const float* init_mv    = (const float*)d_in[6];
    const float* erase_w    = (const float*)d_in[7];
    const float* erase_b    = (const float*)d_in[8];
    const float* add_w      = (const float*)d_in[9];
    const float* add_b      = (const float*)d_in[10];
    const float* read_w     = (const float*)d_in[11];
    const float* read_b     = (const float*)d_in[12];
    const float* pred_w     = (const float*)d_in[13];
    const float* pred_b     = (const float*)d_in[14];
    float* out = (float*)d_out;
    float* ws  = (float*)d_ws;

    float* w_all = ws + W_OFF;
    float* EA    = ws + EA_OFF;
    float* R     = ws + R_OFF;
    float* acc   = ws + ACC_OFF;

    k_pre<<<NSCB + NROW / 64, 256, 0, stream>>>(q_data, q_embed_w, mem_key,
                                                qa_data, qa_embed_w,
                                                erase_w, erase_b, add_w, add_b,
                                                w_all, EA, acc);
    k_scan<<<BB * 2, 512, 0, stream>>>(w_all, EA, init_mv, R);
    k_fc<<<NFCB, 256, 0, stream>>>(R, q_data, q_embed_w, read_w, read_b,
                                   pred_w, pred_b, target, out, acc);
}